// Round 5
// baseline (464.646 us; speedup 1.0000x reference)
//
#include <hip/hip_runtime.h>
#include <math.h>

#define NATOMS 25000
#define NPAIRS 400000
#define XSIZE (NATOMS * 32 * 9)   // 7,200,000 floats; radial output follows
#define TWO_PI 6.28318530717958647692f
#define WPB 8    // atoms (waves) per k_fused block

__device__ __forceinline__ float silu_f(float x) { return x / (1.0f + expf(-x)); }

// ---------------- K0: fused EW build (25 blocks) + pair counting ----------------
// EW[tab*3200 + z*32 + f]: tab 0 -> w_zij cols 0..31 (atom i), tab 1 -> cols 32..63 (atom j)
__global__ void k_cnt_ew(const int* __restrict__ pidx, int* __restrict__ counts,
                         const float* __restrict__ emb, const float* __restrict__ wz,
                         float* __restrict__ EW) {
    if (blockIdx.x < 25) {
        int t = blockIdx.x * 256 + threadIdx.x;
        if (t >= 2 * 100 * 32) return;
        int tab = t / 3200;
        int rem = t - tab * 3200;
        int z = rem >> 5;
        int f = rem & 31;
        const float* e = emb + z * 32;
        const float* w = wz + f * 64 + tab * 32;
        float acc = 0.f;
#pragma unroll
        for (int k = 0; k < 32; k++) acc += e[k] * w[k];
        EW[t] = acc;
    } else {
        int p = (blockIdx.x - 25) * 256 + threadIdx.x;
        if (p >= NPAIRS) return;
        atomicAdd(&counts[pidx[p]], 1);
    }
}

// ---------------- K1: exclusive scan of counts -> offsets (single block) ----------------
__global__ __launch_bounds__(1024) void k_scan(const int* __restrict__ counts,
                                               int* __restrict__ offsets) {
    __shared__ int part[1024];
    const int t = threadIdx.x;
    const int base = t * 25;  // 1024*25 = 25600 >= NATOMS
    int mysum = 0;
    for (int i = 0; i < 25; i++) {
        int idx = base + i;
        mysum += (idx < NATOMS) ? counts[idx] : 0;
    }
    part[t] = mysum;
    __syncthreads();
    for (int off = 1; off < 1024; off <<= 1) {
        int v = (t >= off) ? part[t - off] : 0;
        __syncthreads();
        part[t] += v;
        __syncthreads();
    }
    int excl = part[t] - mysum;
    for (int i = 0; i < 25; i++) {
        int idx = base + i;
        if (idx < NATOMS) {
            offsets[idx] = excl;
            excl += counts[idx];
        }
    }
    if (t == 1023) offsets[NATOMS] = part[1023];
}

// ---------------- K2: compact, atom-sorted per-slot records ----------------
// qz[slot] = (pair id, packed species); rd4[slot] = (d, rx, ry, rz).
__global__ void k_fill(const int* __restrict__ pidx, const int* __restrict__ anum,
                       const float* __restrict__ r_ij, const float* __restrict__ d_ij,
                       const int* __restrict__ offsets, int* __restrict__ cursor,
                       int2* __restrict__ qz, float4* __restrict__ rd4) {
    int p = blockIdx.x * 256 + threadIdx.x;
    if (p >= NPAIRS) return;
    int a = pidx[p];
    int aj = pidx[NPAIRS + p];
    int j = atomicAdd(&cursor[a], 1);
    int slot = offsets[a] + j;
    qz[slot] = make_int2(p, (anum[a] << 16) | anum[aj]);
    rd4[slot] = make_float4(d_ij[p], r_ij[3 * p], r_ij[3 * p + 1], r_ij[3 * p + 2]);
}

// ---------------- K3: fully fused per-atom kernel ----------------
// 512 threads = 8 waves = 8 atoms/block. lane = (f 0..31, h 0..1).
// Per iteration the wave processes 2 slots (A = even, B = odd):
//   - half h computes radial for ITS pair, stages 64 radial values in
//     wave-private LDS, K-split matvec via float4 LDS reads (lane holds 16
//     weights per matrix; shfl_xor(32) combines K-halves -> no spill, no
//     coef workspace roundtrip).
//   - accumulates the 10 tensor components for its own pair; epilogue is
//     round-4's (per-wave-private LDS, no cross-wave barriers after staging).
// NOTE: __launch_bounds__(N,1) ONLY — any min-occupancy bound makes this
// compiler spill to scratch (rounds 2 & 4: +120 MB phantom HBM traffic).
__global__ __launch_bounds__(512, 1) void k_fused(
    const int2* __restrict__ qz, const float4* __restrict__ rd4,
    const int* __restrict__ offsets,
    const float* __restrict__ EW, const float* __restrict__ b_zij,
    const float* __restrict__ w_I, const float* __restrict__ b_I,
    const float* __restrict__ w_A, const float* __restrict__ b_A,
    const float* __restrict__ w_S, const float* __restrict__ b_S,
    const float* __restrict__ w_t0, const float* __restrict__ w_t1,
    const float* __restrict__ w_t2,
    const float* __restrict__ w_s1, const float* __restrict__ b_s1,
    const float* __restrict__ w_s2, const float* __restrict__ b_s2,
    const float* __restrict__ ln_w, const float* __restrict__ ln_b,
    float* __restrict__ out) {
    __shared__ float ws1t[32 * 65];       // 8.3 KB  [k][o]
    __shared__ float ws2t[64 * 97];       // 24.8 KB [k][o]
    __shared__ float wt0t[32 * 33];       // 4.2 KB  [f][g]
    __shared__ float wt1t[32 * 33];
    __shared__ float wt2t[32 * 33];
    __shared__ float radw[WPB][64];       // 2 KB, wave-private radial staging
    __shared__ float h_st[WPB][32];
    __shared__ float h1_st[WPB][64];
    __shared__ float h2_st[WPB][96];
    __shared__ float vals_st[WPB][320];   // 10 comps x 32f; reused as X staging
    // total 64.25 KB -> 2 blocks/CU (128.5 of 160 KB), 16 waves/CU

    const int tid = threadIdx.x;
    for (int i = tid; i < 64 * 32; i += 512) { int o = i >> 5, ff = i & 31; ws1t[ff * 65 + o] = w_s1[i]; }
    for (int i = tid; i < 96 * 64; i += 512) { int o = i >> 6, k = i & 63; ws2t[k * 97 + o] = w_s2[i]; }
    for (int i = tid; i < 32 * 32; i += 512) {
        int g = i >> 5, ff = i & 31;
        wt0t[ff * 33 + g] = w_t0[i];
        wt1t[ff * 33 + g] = w_t1[i];
        wt2t[ff * 33 + g] = w_t2[i];
    }
    __syncthreads();

    const int wave = tid >> 6;
    const int lane = tid & 63;
    const int f = lane & 31;
    const int h = lane >> 5;          // k-half AND slot-parity role
    const int atom = blockIdx.x * WPB + wave;

    // 16 weights per matrix per lane (K-split): k in [16h, 16h+16)
    float wIr[16], wAr[16], wSr[16];
#pragma unroll
    for (int j = 0; j < 16; j++) {
        int k = h * 16 + j;
        wIr[j] = w_I[f * 32 + k];
        wAr[j] = w_A[f * 32 + k];
        wSr[j] = w_S[f * 32 + k];
    }
    const float bIv = b_I[f], bAv = b_A[f], bSv = b_S[f], bzv = b_zij[f];

    const float start0 = 0.006737946999085467f;          // exp(-5)
    const float step = (1.0f - start0) * (1.0f / 31.0f);
    const float tmp = 0.0625f * (1.0f - start0);
    const float bconst = 1.0f / (tmp * tmp);
    const float center = start0 + (float)f * step;

    float sI = 0.f, vA0 = 0.f, vA1 = 0.f, vA2 = 0.f;
    float Sxx = 0.f, Sxy = 0.f, Sxz = 0.f, Syy = 0.f, Syz = 0.f, Szz = 0.f;

    const int seg0 = offsets[atom];
    const int cnt = offsets[atom + 1] - seg0;
    float* __restrict__ out_rad = out + XSIZE;

    for (int t0 = 0; t0 < cnt; t0 += 2) {
        const bool hasB = (t0 + 1) < cnt;
        const int s_own = seg0 + ((h && hasB) ? t0 + 1 : t0);
        const bool act = (h == 0) || hasB;     // h=1 is a duplicate when !hasB

        const int2 q = qz[s_own];              // broadcast within half-wave
        const float4 rv = rd4[s_own];

        float d = rv.x;
        float invd = 1.0f / d;
        float hx = rv.y * invd, hy = rv.z * invd, hz = rv.w * invd;
        float rcut = (d < 0.5f) ? 0.5f * (cosf(d * TWO_PI) + 1.0f) : 0.0f;
        float ee = expf(-10.0f * d);
        float diff = ee - center;
        float radf = expf(-bconst * diff * diff) * rcut;
        if (act) out_rad[(long)q.x * 32 + f] = radf;   // 128B-aligned full-line write

        radw[wave][lane] = radf;               // stage: A radial in 0..31, B in 32..63
        __builtin_amdgcn_wave_barrier();       // keep LDS write before reads

        // K-split matvec partials for both pairs via float4 LDS reads
        float pIA = 0.f, pAA = 0.f, pSA = 0.f, pIB = 0.f, pAB = 0.f, pSB = 0.f;
#pragma unroll
        for (int blk = 0; blk < 4; blk++) {
            float4 ra = *(const float4*)&radw[wave][16 * h + 4 * blk];
            float4 rb = *(const float4*)&radw[wave][32 + 16 * h + 4 * blk];
            pIA += ra.x * wIr[4 * blk + 0] + ra.y * wIr[4 * blk + 1] + ra.z * wIr[4 * blk + 2] + ra.w * wIr[4 * blk + 3];
            pAA += ra.x * wAr[4 * blk + 0] + ra.y * wAr[4 * blk + 1] + ra.z * wAr[4 * blk + 2] + ra.w * wAr[4 * blk + 3];
            pSA += ra.x * wSr[4 * blk + 0] + ra.y * wSr[4 * blk + 1] + ra.z * wSr[4 * blk + 2] + ra.w * wSr[4 * blk + 3];
            pIB += rb.x * wIr[4 * blk + 0] + rb.y * wIr[4 * blk + 1] + rb.z * wIr[4 * blk + 2] + rb.w * wIr[4 * blk + 3];
            pAB += rb.x * wAr[4 * blk + 0] + rb.y * wAr[4 * blk + 1] + rb.z * wAr[4 * blk + 2] + rb.w * wAr[4 * blk + 3];
            pSB += rb.x * wSr[4 * blk + 0] + rb.y * wSr[4 * blk + 1] + rb.z * wSr[4 * blk + 2] + rb.w * wSr[4 * blk + 3];
        }
        __builtin_amdgcn_wave_barrier();       // reads done before next iter's write
        float fIA = pIA + __shfl_xor(pIA, 32, 64) + bIv;
        float fAA = pAA + __shfl_xor(pAA, 32, 64) + bAv;
        float fSA = pSA + __shfl_xor(pSA, 32, 64) + bSv;
        float fIB = pIB + __shfl_xor(pIB, 32, 64) + bIv;
        float fAB = pAB + __shfl_xor(pAB, 32, 64) + bAv;
        float fSB = pSB + __shfl_xor(pSB, 32, 64) + bSv;

        float zf = EW[(q.y >> 16) * 32 + f] + EW[3200 + (q.y & 0xffff) * 32 + f] + bzv;
        float C = rcut * zf;
        float aI = (h ? fIB : fIA) * C;
        float aA = (h ? fAB : fAA) * C;
        float aS = (h ? fSB : fSA) * C;

        if (act) {
            sI += aI;
            vA0 += aA * hx; vA1 += aA * hy; vA2 += aA * hz;
            Sxx += aS * (hx * hx - (1.0f / 3.0f));
            Sxy += aS * (hx * hy);
            Sxz += aS * (hx * hz);
            Syy += aS * (hy * hy - (1.0f / 3.0f));
            Syz += aS * (hy * hz);
            Szz += aS * (hz * hz - (1.0f / 3.0f));
        }
    }
    // combine half-wave partial sums (h=0 held even slots, h=1 odd slots)
    sI += __shfl_xor(sI, 32, 64);
    vA0 += __shfl_xor(vA0, 32, 64);
    vA1 += __shfl_xor(vA1, 32, 64);
    vA2 += __shfl_xor(vA2, 32, 64);
    Sxx += __shfl_xor(Sxx, 32, 64);
    Sxy += __shfl_xor(Sxy, 32, 64);
    Sxz += __shfl_xor(Sxz, 32, 64);
    Syy += __shfl_xor(Syy, 32, 64);
    Syz += __shfl_xor(Syz, 32, 64);
    Szz += __shfl_xor(Szz, 32, 64);

    // norm2 of I+A+S for feature f
    float M00 = sI + Sxx, M01 = -vA2 + Sxy, M02 = vA1 + Sxz;
    float M10 = vA2 + Sxy, M11 = sI + Syy, M12 = -vA0 + Syz;
    float M20 = -vA1 + Sxz, M21 = vA0 + Syz, M22 = sI + Szz;
    float norm2 = M00 * M00 + M01 * M01 + M02 * M02 + M10 * M10 + M11 * M11 +
                  M12 * M12 + M20 * M20 + M21 * M21 + M22 * M22;

    // LayerNorm over 32 features (each f present in both halves -> /64)
    float mu = norm2;
#pragma unroll
    for (int m = 32; m >= 1; m >>= 1) mu += __shfl_xor(mu, m, 64);
    mu *= (1.0f / 64.0f);
    float dd = norm2 - mu;
    float vv = dd * dd;
#pragma unroll
    for (int m = 32; m >= 1; m >>= 1) vv += __shfl_xor(vv, m, 64);
    vv *= (1.0f / 64.0f);
    float hval = dd * rsqrtf(vv + 1e-5f) * ln_w[f] + ln_b[f];
    if (h == 0) h_st[wave][f] = hval;

    // MLP1: 64 outputs (same-wave LDS, lockstep-ordered)
    {
        float acc = b_s1[lane];
#pragma unroll
        for (int k = 0; k < 32; k++) acc += h_st[wave][k] * ws1t[k * 65 + lane];
        h1_st[wave][lane] = silu_f(acc);
    }

    // MLP2: 96 outputs
    {
        float acc = b_s2[lane];
        float acc2 = (lane < 32) ? b_s2[64 + lane] : 0.f;
#pragma unroll
        for (int k = 0; k < 64; k++) {
            float hk = h1_st[wave][k];
            acc += hk * ws2t[k * 97 + lane];
            if (lane < 32) acc2 += hk * ws2t[k * 97 + 64 + lane];
        }
        h2_st[wave][lane] = silu_f(acc);
        if (lane < 32) h2_st[wave][64 + lane] = silu_f(acc2);
    }

    // stage per-f tensor components
    if (h == 0) {
        vals_st[wave][0 * 32 + f] = sI;
        vals_st[wave][1 * 32 + f] = vA0;
        vals_st[wave][2 * 32 + f] = vA1;
        vals_st[wave][3 * 32 + f] = vA2;
        vals_st[wave][4 * 32 + f] = Sxx;
        vals_st[wave][5 * 32 + f] = Sxy;
        vals_st[wave][6 * 32 + f] = Sxz;
        vals_st[wave][7 * 32 + f] = Syy;
        vals_st[wave][8 * 32 + f] = Syz;
        vals_st[wave][9 * 32 + f] = Szz;
    }

    // channel mixing + combine with s3; X staged back into vals_st
    {
        const int g = f;
        float mI = 0.f, mA0 = 0.f, mA1 = 0.f, mA2 = 0.f;
        float mSxx = 0.f, mSxy = 0.f, mSxz = 0.f, mSyy = 0.f, mSyz = 0.f, mSzz = 0.f;
        const float* V = vals_st[wave];
#pragma unroll 8
        for (int ff = 0; ff < 32; ff++) {
            float w0 = wt0t[ff * 33 + g];
            float w1 = wt1t[ff * 33 + g];
            float w2 = wt2t[ff * 33 + g];
            mI += w0 * V[ff];
            mA0 += w1 * V[32 + ff];
            mA1 += w1 * V[64 + ff];
            mA2 += w1 * V[96 + ff];
            mSxx += w2 * V[128 + ff];
            mSxy += w2 * V[160 + ff];
            mSxz += w2 * V[192 + ff];
            mSyy += w2 * V[224 + ff];
            mSyz += w2 * V[256 + ff];
            mSzz += w2 * V[288 + ff];
        }
        float s0 = h2_st[wave][g * 3 + 0];
        float s1 = h2_st[wave][g * 3 + 1];
        float s2 = h2_st[wave][g * 3 + 2];
        float* X = vals_st[wave];
        if (h == 0) {
            X[g * 9 + 0] = s0 * mI + s2 * mSxx;
            X[g * 9 + 1] = -s1 * mA2 + s2 * mSxy;
            X[g * 9 + 2] = s1 * mA1 + s2 * mSxz;
            X[g * 9 + 3] = s1 * mA2 + s2 * mSxy;
            X[g * 9 + 4] = s0 * mI + s2 * mSyy;
        } else {
            X[g * 9 + 5] = -s1 * mA0 + s2 * mSyz;
            X[g * 9 + 6] = -s1 * mA1 + s2 * mSxz;
            X[g * 9 + 7] = s1 * mA0 + s2 * mSyz;
            X[g * 9 + 8] = s0 * mI + s2 * mSzz;
        }
    }

    // coalesced X write: 288 contiguous floats per atom
    {
        float* dst = out + (long)atom * 288;
        const float* xs = vals_st[wave];
#pragma unroll
        for (int c = 0; c < 5; c++) {
            int i = lane + c * 64;
            if (i < 288) dst[i] = xs[i];
        }
    }
}

extern "C" void kernel_launch(void* const* d_in, const int* in_sizes, int n_in,
                              void* d_out, int out_size, void* d_ws, size_t ws_size,
                              hipStream_t stream) {
    const int* anum = (const int*)d_in[0];
    const int* pidx = (const int*)d_in[1];
    const float* r_ij = (const float*)d_in[2];
    const float* d_ijp = (const float*)d_in[3];
    const float* emb = (const float*)d_in[4];
    const float* w_zij = (const float*)d_in[5];
    const float* b_zij = (const float*)d_in[6];
    const float* w_I = (const float*)d_in[7];
    const float* b_I = (const float*)d_in[8];
    const float* w_A = (const float*)d_in[9];
    const float* b_A = (const float*)d_in[10];
    const float* w_S = (const float*)d_in[11];
    const float* b_S = (const float*)d_in[12];
    const float* w_t0 = (const float*)d_in[13];
    const float* w_t1 = (const float*)d_in[14];
    const float* w_t2 = (const float*)d_in[15];
    const float* w_s1 = (const float*)d_in[16];
    const float* b_s1 = (const float*)d_in[17];
    const float* w_s2 = (const float*)d_in[18];
    const float* b_s2 = (const float*)d_in[19];
    const float* ln_w = (const float*)d_in[20];
    const float* ln_b = (const float*)d_in[21];
    float* out = (float*)d_out;

    // workspace layout (~16 MB), 16B-aligned where vector-loaded
    float* EW = (float*)d_ws;                                   // 6400 f
    int* counts = (int*)(EW + 6400);                            // 25000 i
    int* cursor = counts + NATOMS;                              // 25000 i
    int* offsets = cursor + NATOMS;                             // 25002 i (+pad to even)
    float4* rd4 = (float4*)(offsets + NATOMS + 2);              // 400000 float4
    int2* qz = (int2*)(rd4 + NPAIRS);                           // 400000 int2

    hipMemsetAsync(counts, 0, 2 * NATOMS * sizeof(int), stream);  // counts + cursor
    k_cnt_ew<<<25 + (NPAIRS + 255) / 256, 256, 0, stream>>>(pidx, counts, emb, w_zij, EW);
    k_scan<<<1, 1024, 0, stream>>>(counts, offsets);
    k_fill<<<(NPAIRS + 255) / 256, 256, 0, stream>>>(pidx, anum, r_ij, d_ijp,
                                                     offsets, cursor, qz, rd4);
    k_fused<<<NATOMS / WPB, 512, 0, stream>>>(qz, rd4, offsets, EW, b_zij,
                                              w_I, b_I, w_A, b_A, w_S, b_S,
                                              w_t0, w_t1, w_t2, w_s1, b_s1,
                                              w_s2, b_s2, ln_w, ln_b, out);
}